// Round 6
// baseline (118.950 us; speedup 1.0000x reference)
//
#include <hip/hip_runtime.h>

// SpatialAttention G=2,N=192,D=64,H=4,DK=16 — round 4 design, compile fix:
// cvt_pkrtz returns __fp16x2 -> bit_cast to _Float16x2 (zero-cost).
// Prologue kernel: W^T -> f16 in d_ws (Q-scale folded). Main kernel: 768
// blocks (2 per (g,n), 96 t-rows each) x 512 thr; LDS = X(24K)+VT(24K);
// W fragments register-loaded from L2-broadcast ws. 6 waves/SIMD.

typedef float    f32x4 __attribute__((ext_vector_type(4)));
typedef float    f32x2 __attribute__((ext_vector_type(2)));
typedef _Float16 f16x2 __attribute__((ext_vector_type(2)));
typedef _Float16 f16x4 __attribute__((ext_vector_type(4)));
typedef _Float16 f16x8 __attribute__((ext_vector_type(8)));

// [.][64] f16 tile, 16B blocks, XOR row&7 (b128 conflict-free)
__device__ __forceinline__ int xsw64(int r, int c) {
    return (r << 6) + (((c >> 3) ^ (r & 7)) << 3) + (c & 7);
}
// [.][192] f16 tile, 16B blocks, XOR row&7
__device__ __forceinline__ int vsw192(int r, int c) {
    return r * 192 + ((((c >> 3) ^ (r & 7)) & 31) << 3) + (c & 7);
}

#define QSCALE 0.36067376022224085f  /* 0.25 * log2(e) */

// ---------------- prologue: W^T f32->f16 into ws, biases ----------------
extern "C" __global__ void spa_prep(const float* __restrict__ Wq, const float* __restrict__ bq,
                                    const float* __restrict__ Wk, const float* __restrict__ bk,
                                    const float* __restrict__ Wv, const float* __restrict__ bv,
                                    const float* __restrict__ Wo, const float* __restrict__ bo,
                                    _Float16* __restrict__ WT, float* __restrict__ BS) {
    const int t = blockIdx.x * 256 + threadIdx.x;   // 0..4095
    const int m  = t >> 10;
    const int e  = (t >> 4) & 63;
    const int d0 = (t & 15) << 2;
    const float* W[4] = {Wq, Wk, Wv, Wo};
    const float s = (m == 0) ? QSCALE : 1.0f;
    f16x4 h4;
#pragma unroll
    for (int j = 0; j < 4; ++j) h4[j] = (_Float16)(W[m][(d0 + j) * 64 + e] * s);
    *(f16x4*)&WT[(m << 12) + (e << 6) + d0] = h4;
    if (t < 256) {
        const int mm = t >> 6, ee = t & 63;
        const float* B[4] = {bq, bk, bv, bo};
        BS[t] = B[mm][ee] * ((mm == 0) ? QSCALE : 1.0f);
    }
}

// ---------------- main fused kernel ----------------
extern "C" __global__ void __launch_bounds__(512, 6)
spa_mfma3(const float* __restrict__ adj,
          const _Float16* __restrict__ WTg, const float* __restrict__ BS,
          float* __restrict__ out) {
    extern __shared__ __align__(16) char smem[];
    _Float16* X  = (_Float16*)smem;           // [192][64] xsw64 (tokens; half becomes attn out)
    _Float16* VT = (_Float16*)smem + 12288;   // [64][192] vsw192

    const int tid  = threadIdx.x;
    const int l    = tid & 63;
    const int wv   = tid >> 6;     // 0..7
    const int l15  = l & 15;
    const int g    = l >> 4;       // 0..3
    const int gn   = blockIdx.x >> 1;
    const int half = blockIdx.x & 1;
    const int ttb  = half * 6;     // this block's t-tile base (6 tiles = 96 rows)

    const float* Xg   = adj + (size_t)gn * (192 * 64);
    float*       outg = out + (size_t)gn * (192 * 64);

    const int h  = wv >> 1;
    const int eh = h << 4;
    const int et = wv & 3;

    // W fragments (L2-broadcast, linear [m][e][d] f16):
    const f16x8 wv0 = *(const f16x8*)&WTg[(2 << 12) + (((et << 4) + l15) << 6) + (g << 3)];
    const f16x8 wv1 = *(const f16x8*)&WTg[(2 << 12) + (((et << 4) + l15) << 6) + 32 + (g << 3)];
    const f16x8 wk0 = *(const f16x8*)&WTg[(1 << 12) + ((eh + l15) << 6) + (g << 3)];
    const f16x8 wk1 = *(const f16x8*)&WTg[(1 << 12) + ((eh + l15) << 6) + 32 + (g << 3)];
    const f16x8 wq0 = *(const f16x8*)&WTg[(0 << 12) + ((eh + l15) << 6) + (g << 3)];
    const f16x8 wq1 = *(const f16x8*)&WTg[(0 << 12) + ((eh + l15) << 6) + 32 + (g << 3)];
    const f32x4 bv4 = *(const f32x4*)&BS[128 + (et << 4) + (g << 2)];
    const f32x4 bk4 = *(const f32x4*)&BS[64 + eh + (g << 2)];
    const f32x4 bq4 = *(const f32x4*)&BS[0 + eh + (g << 2)];

    // ---- stage X -> f16 LDS (full 192 rows; K/V need all tokens) ----
    {
        const int d0 = (tid & 7) << 3;
        const int t0 = tid >> 3;
#pragma unroll
        for (int p = 0; p < 3; ++p) {
            int t = t0 + (p << 6);
            const float4* src = (const float4*)&Xg[(t << 6) + d0];
            float4 v0 = src[0], v1 = src[1];
            f16x8 h8;
            h8[0]=(_Float16)v0.x; h8[1]=(_Float16)v0.y; h8[2]=(_Float16)v0.z; h8[3]=(_Float16)v0.w;
            h8[4]=(_Float16)v1.x; h8[5]=(_Float16)v1.y; h8[6]=(_Float16)v1.z; h8[7]=(_Float16)v1.w;
            *(f16x8*)&X[xsw64(t, d0)] = h8;
        }
    }
    __syncthreads();

    const f32x4 z = {0.f, 0.f, 0.f, 0.f};

    // ---- VT: head et, s-tiles (wv>>2)*6 .. +6 (full 192 s-rows per block) ----
    {
        const int stb = (wv >> 2) * 6;
        for (int s6 = 0; s6 < 6; ++s6) {
            int st = stb + s6;
            f16x8 x0 = *(const f16x8*)&X[xsw64((st << 4) + l15, g << 3)];
            f16x8 x1 = *(const f16x8*)&X[xsw64((st << 4) + l15, 32 + (g << 3))];
            f32x4 c = __builtin_amdgcn_mfma_f32_16x16x32_f16(wv0, x0, z, 0, 0, 0);
            c = __builtin_amdgcn_mfma_f32_16x16x32_f16(wv1, x1, c, 0, 0, 0);
            int s = (st << 4) + l15;
#pragma unroll
            for (int r = 0; r < 4; ++r)
                VT[vsw192((et << 4) + (g << 2) + r, s)] = (_Float16)(c[r] + bv4[r]);
        }
    }

    // ---- K fragments in-register (full 192 s-rows) ----
    f16x4 kf[12];
#pragma unroll
    for (int st = 0; st < 12; ++st) {
        f16x8 x0 = *(const f16x8*)&X[xsw64((st << 4) + l15, g << 3)];
        f16x8 x1 = *(const f16x8*)&X[xsw64((st << 4) + l15, 32 + (g << 3))];
        f32x4 c = __builtin_amdgcn_mfma_f32_16x16x32_f16(wk0, x0, z, 0, 0, 0);
        c = __builtin_amdgcn_mfma_f32_16x16x32_f16(wk1, x1, c, 0, 0, 0);
#pragma unroll
        for (int r = 0; r < 4; ++r) kf[st][r] = (_Float16)(c[r] + bk4[r]);
    }

    // ---- Q fragments: this block's 96 rows, 3 t-tiles per wave ----
    f16x4 qf[3];
    const int tloc = (wv & 1) * 3;   // local tile base within the half
#pragma unroll
    for (int j = 0; j < 3; ++j) {
        int tt = ttb + tloc + j;
        f16x8 x0 = *(const f16x8*)&X[xsw64((tt << 4) + l15, g << 3)];
        f16x8 x1 = *(const f16x8*)&X[xsw64((tt << 4) + l15, 32 + (g << 3))];
        f32x4 c = __builtin_amdgcn_mfma_f32_16x16x32_f16(wq0, x0, z, 0, 0, 0);
        c = __builtin_amdgcn_mfma_f32_16x16x32_f16(wq1, x1, c, 0, 0, 0);
#pragma unroll
        for (int r = 0; r < 4; ++r) qf[j][r] = (_Float16)(c[r] + bq4[r]);
    }
    __syncthreads();   // VT done; all X reads done (attn may overwrite X)

    // ---- vf: PV A-frags from VT ----
    f16x4 vf[12];
#pragma unroll
    for (int st = 0; st < 12; ++st)
        vf[st] = *(const f16x4*)&VT[vsw192(eh + l15, (st << 4) + (g << 2))];

    // ---- attention: 3 t-tiles; P stays in registers ----
    for (int j = 0; j < 3; ++j) {
        f32x4 accA = z, accB = z;
        f32x2 rs = {0.f, 0.f};
#pragma unroll
        for (int st = 0; st < 12; ++st) {
            f32x4 c = __builtin_amdgcn_mfma_f32_16x16x16f16(kf[st], qf[j], z, 0, 0, 0);
            float p0 = exp2f(c[0]), p1 = exp2f(c[1]);
            float p2 = exp2f(c[2]), p3 = exp2f(c[3]);
            rs += (f32x2){p0, p1} + (f32x2){p2, p3};
            f16x2 lo = __builtin_bit_cast(f16x2, __builtin_amdgcn_cvt_pkrtz(p0, p1));
            f16x2 hi = __builtin_bit_cast(f16x2, __builtin_amdgcn_cvt_pkrtz(p2, p3));
            f16x4 pf = __builtin_shufflevector(lo, hi, 0, 1, 2, 3);
            if (st & 1) accB = __builtin_amdgcn_mfma_f32_16x16x16f16(vf[st], pf, accB, 0, 0, 0);
            else        accA = __builtin_amdgcn_mfma_f32_16x16x16f16(vf[st], pf, accA, 0, 0, 0);
        }
        float rsum = rs[0] + rs[1];
        rsum += __shfl_xor(rsum, 16);
        rsum += __shfl_xor(rsum, 32);
        const float rinv = 1.0f / rsum;
        f16x4 o4;
#pragma unroll
        for (int r = 0; r < 4; ++r) o4[r] = (_Float16)((accA[r] + accB[r]) * rinv);
        *(f16x4*)&X[xsw64(((ttb + tloc + j) << 4) + l15, eh + (g << 2))] = o4;
    }
    __syncthreads();

    // ---- O-projection of this block's 96 rows -> global ----
    {
        const int eo = ((wv & 3) << 4) + l15;
        const f16x8 wo0 = *(const f16x8*)&WTg[(3 << 12) + (eo << 6) + (g << 3)];
        const f16x8 wo1 = *(const f16x8*)&WTg[(3 << 12) + (eo << 6) + 32 + (g << 3)];
        const float bov = BS[192 + eo];
#pragma unroll
        for (int i = 0; i < 3; ++i) {
            int tt = ttb + ((wv + (i << 3)) >> 2);
            f16x8 a0 = *(const f16x8*)&X[xsw64((tt << 4) + l15, g << 3)];
            f16x8 a1 = *(const f16x8*)&X[xsw64((tt << 4) + l15, 32 + (g << 3))];
            f32x4 c = __builtin_amdgcn_mfma_f32_16x16x32_f16(a0, wo0, z, 0, 0, 0);
            c = __builtin_amdgcn_mfma_f32_16x16x32_f16(a1, wo1, c, 0, 0, 0);
#pragma unroll
            for (int r = 0; r < 4; ++r)
                outg[(((tt << 4) + (g << 2) + r) << 6) + eo] = c[r] + bov;
        }
    }
}

extern "C" void kernel_launch(void* const* d_in, const int* in_sizes, int n_in,
                              void* d_out, int out_size, void* d_ws, size_t ws_size,
                              hipStream_t stream) {
    (void)in_sizes; (void)n_in; (void)ws_size; (void)out_size;
    const float* adj = (const float*)d_in[0];
    _Float16* WT = (_Float16*)d_ws;                       // 32 KiB f16 W^T
    float*    BS = (float*)((char*)d_ws + 32768);         // 1 KiB biases

    spa_prep<<<16, 256, 0, stream>>>((const float*)d_in[1], (const float*)d_in[2],
                                     (const float*)d_in[3], (const float*)d_in[4],
                                     (const float*)d_in[5], (const float*)d_in[6],
                                     (const float*)d_in[7], (const float*)d_in[8],
                                     WT, BS);

    const int shmem = 49152;  // 48 KiB: X 24K + VT 24K -> 3 blocks/CU capacity
    spa_mfma3<<<2 * 192 * 2, 512, shmem, stream>>>(adj, WT, BS, (float*)d_out);
}

// Round 8
// 113.631 us; speedup vs baseline: 1.0468x; 1.0468x over previous
//
#include <hip/hip_runtime.h>

// SpatialAttention G=2,N=192,D=64,H=4,DK=16 — round 7 kernel (resubmit;
// round-7 bench failed with container infra error, kernel never ran).
// Single kernel, 384 blocks (one per (g,n)) x 512 thr (8 waves).
// LDS = X(24K) + VT(24K) only; W fragments gathered from global (L2-hot)
// into registers. Attention t-tile loop unrolled x2 for two independent
// MFMA->exp->MFMA chains per wave. No d_ws use.

typedef float    f32x4 __attribute__((ext_vector_type(4)));
typedef float    f32x2 __attribute__((ext_vector_type(2)));
typedef _Float16 f16x2 __attribute__((ext_vector_type(2)));
typedef _Float16 f16x4 __attribute__((ext_vector_type(4)));
typedef _Float16 f16x8 __attribute__((ext_vector_type(8)));

// [.][64] f16 tile, 16B blocks, XOR row&7 (b128 conflict-free)
__device__ __forceinline__ int xsw64(int r, int c) {
    return (r << 6) + (((c >> 3) ^ (r & 7)) << 3) + (c & 7);
}
// [.][192] f16 tile, 16B blocks, XOR row&7
__device__ __forceinline__ int vsw192(int r, int c) {
    return r * 192 + ((((c >> 3) ^ (r & 7)) & 31) << 3) + (c & 7);
}

#define QSCALE 0.36067376022224085f  /* 0.25 * log2(e) */

extern "C" __global__ void __launch_bounds__(512, 3)
spa_mfma4(const float* __restrict__ adj,
          const float* __restrict__ Wq, const float* __restrict__ bq,
          const float* __restrict__ Wk, const float* __restrict__ bk,
          const float* __restrict__ Wv, const float* __restrict__ bv,
          const float* __restrict__ Wo, const float* __restrict__ bo,
          float* __restrict__ out) {
    extern __shared__ __align__(16) char smem[];
    _Float16* X  = (_Float16*)smem;           // [192][64] xsw64 (tokens; later attn out)
    _Float16* VT = (_Float16*)smem + 12288;   // [64][192] vsw192

    const int tid = threadIdx.x;
    const int l   = tid & 63;
    const int wv  = tid >> 6;     // 0..7
    const int l15 = l & 15;
    const int g   = l >> 4;       // 0..3

    const float* Xg   = adj + (size_t)blockIdx.x * (192 * 64);
    float*       outg = out + (size_t)blockIdx.x * (192 * 64);

    const int h  = wv >> 1;       // head this wave attends
    const int eh = h << 4;
    const int et = wv & 3;        // head whose VT slice this wave computes
    const int ew = eh + l15;                 // q/k W-frag column
    const int ev = ((wv & 3) << 4) + l15;    // v W-frag row / o W-frag column

    // ---- W fragments: gathered from global (L2-broadcast), f32->f16 ----
    f16x8 wq0, wq1, wk0, wk1, wvv0, wvv1;
#pragma unroll
    for (int jd = 0; jd < 8; ++jd) {
        const int d0 = (g << 3) + jd;
        wq0[jd]  = (_Float16)(Wq[d0 * 64 + ew] * QSCALE);
        wq1[jd]  = (_Float16)(Wq[(32 + d0) * 64 + ew] * QSCALE);
        wk0[jd]  = (_Float16)(Wk[d0 * 64 + ew]);
        wk1[jd]  = (_Float16)(Wk[(32 + d0) * 64 + ew]);
        wvv0[jd] = (_Float16)(Wv[d0 * 64 + ev]);
        wvv1[jd] = (_Float16)(Wv[(32 + d0) * 64 + ev]);
    }
    f32x4 bq4 = *(const f32x4*)&bq[eh + (g << 2)];
#pragma unroll
    for (int r = 0; r < 4; ++r) bq4[r] *= QSCALE;
    const f32x4 bk4 = *(const f32x4*)&bk[eh + (g << 2)];
    const f32x4 bv4 = *(const f32x4*)&bv[((wv & 3) << 4) + (g << 2)];

    // ---- stage X -> f16 LDS (coalesced b128 loads) ----
    {
        const int d0 = (tid & 7) << 3;
        const int t0 = tid >> 3;
#pragma unroll
        for (int p = 0; p < 3; ++p) {
            int t = t0 + (p << 6);
            const float4* src = (const float4*)&Xg[(t << 6) + d0];
            float4 v0 = src[0], v1 = src[1];
            f16x8 h8;
            h8[0]=(_Float16)v0.x; h8[1]=(_Float16)v0.y; h8[2]=(_Float16)v0.z; h8[3]=(_Float16)v0.w;
            h8[4]=(_Float16)v1.x; h8[5]=(_Float16)v1.y; h8[6]=(_Float16)v1.z; h8[7]=(_Float16)v1.w;
            *(f16x8*)&X[xsw64(t, d0)] = h8;
        }
    }
    __syncthreads();

    const f32x4 z = {0.f, 0.f, 0.f, 0.f};

    // ---- VT slice: head et, 6 s-tiles (half per wave of the pair) ----
    {
        const int stb = (wv >> 2) * 6;
        for (int s6 = 0; s6 < 6; ++s6) {
            int st = stb + s6;
            f16x8 x0 = *(const f16x8*)&X[xsw64((st << 4) + l15, g << 3)];
            f16x8 x1 = *(const f16x8*)&X[xsw64((st << 4) + l15, 32 + (g << 3))];
            f32x4 c = __builtin_amdgcn_mfma_f32_16x16x32_f16(wvv0, x0, z, 0, 0, 0);
            c = __builtin_amdgcn_mfma_f32_16x16x32_f16(wvv1, x1, c, 0, 0, 0);
            int s = (st << 4) + l15;
#pragma unroll
            for (int r = 0; r < 4; ++r)
                VT[vsw192((et << 4) + (g << 2) + r, s)] = (_Float16)(c[r] + bv4[r]);
        }
    }

    // ---- K fragments in-register (all 192 s-rows; dup x2 per head pair) ----
    f16x4 kf[12];
#pragma unroll
    for (int st = 0; st < 12; ++st) {
        f16x8 x0 = *(const f16x8*)&X[xsw64((st << 4) + l15, g << 3)];
        f16x8 x1 = *(const f16x8*)&X[xsw64((st << 4) + l15, 32 + (g << 3))];
        f32x4 c = __builtin_amdgcn_mfma_f32_16x16x32_f16(wk0, x0, z, 0, 0, 0);
        c = __builtin_amdgcn_mfma_f32_16x16x32_f16(wk1, x1, c, 0, 0, 0);
#pragma unroll
        for (int r = 0; r < 4; ++r) kf[st][r] = (_Float16)(c[r] + bk4[r]);
    }

    // ---- Q fragments: 6 t-tiles (half of 192 rows per wave) ----
    f16x4 qf[6];
    const int tloc = (wv & 1) * 6;
#pragma unroll
    for (int j = 0; j < 6; ++j) {
        int tt = tloc + j;
        f16x8 x0 = *(const f16x8*)&X[xsw64((tt << 4) + l15, g << 3)];
        f16x8 x1 = *(const f16x8*)&X[xsw64((tt << 4) + l15, 32 + (g << 3))];
        f32x4 c = __builtin_amdgcn_mfma_f32_16x16x32_f16(wq0, x0, z, 0, 0, 0);
        c = __builtin_amdgcn_mfma_f32_16x16x32_f16(wq1, x1, c, 0, 0, 0);
#pragma unroll
        for (int r = 0; r < 4; ++r) qf[j][r] = (_Float16)(c[r] + bq4[r]);
    }
    __syncthreads();   // VT complete; all X reads done

    // ---- prefetch O-projection W fragments (hide latency under attention) ----
    f16x8 wo0, wo1;
#pragma unroll
    for (int jd = 0; jd < 8; ++jd) {
        const int d0 = (g << 3) + jd;
        wo0[jd] = (_Float16)(Wo[d0 * 64 + ev]);
        wo1[jd] = (_Float16)(Wo[(32 + d0) * 64 + ev]);
    }
    const float bov = bo[ev];

    // ---- vf: PV A-frags from VT ----
    f16x4 vf[12];
#pragma unroll
    for (int st = 0; st < 12; ++st)
        vf[st] = *(const f16x4*)&VT[vsw192(eh + l15, (st << 4) + (g << 2))];

    // ---- attention: 6 t-tiles, unrolled x2 (two independent chains) ----
#pragma unroll
    for (int jj = 0; jj < 3; ++jj) {
        const int j0 = 2 * jj, j1 = 2 * jj + 1;
        f32x4 accA0 = z, accB0 = z, accA1 = z, accB1 = z;
        f32x2 rs0 = {0.f, 0.f}, rs1 = {0.f, 0.f};
#pragma unroll
        for (int st = 0; st < 12; ++st) {
            f32x4 c0 = __builtin_amdgcn_mfma_f32_16x16x16f16(kf[st], qf[j0], z, 0, 0, 0);
            f32x4 c1 = __builtin_amdgcn_mfma_f32_16x16x16f16(kf[st], qf[j1], z, 0, 0, 0);
            float p00 = exp2f(c0[0]), p01 = exp2f(c0[1]), p02 = exp2f(c0[2]), p03 = exp2f(c0[3]);
            float p10 = exp2f(c1[0]), p11 = exp2f(c1[1]), p12 = exp2f(c1[2]), p13 = exp2f(c1[3]);
            rs0 += (f32x2){p00, p01} + (f32x2){p02, p03};
            rs1 += (f32x2){p10, p11} + (f32x2){p12, p13};
            f16x2 lo0 = __builtin_bit_cast(f16x2, __builtin_amdgcn_cvt_pkrtz(p00, p01));
            f16x2 hi0 = __builtin_bit_cast(f16x2, __builtin_amdgcn_cvt_pkrtz(p02, p03));
            f16x2 lo1 = __builtin_bit_cast(f16x2, __builtin_amdgcn_cvt_pkrtz(p10, p11));
            f16x2 hi1 = __builtin_bit_cast(f16x2, __builtin_amdgcn_cvt_pkrtz(p12, p13));
            f16x4 pf0 = __builtin_shufflevector(lo0, hi0, 0, 1, 2, 3);
            f16x4 pf1 = __builtin_shufflevector(lo1, hi1, 0, 1, 2, 3);
            if (st & 1) {
                accB0 = __builtin_amdgcn_mfma_f32_16x16x16f16(vf[st], pf0, accB0, 0, 0, 0);
                accB1 = __builtin_amdgcn_mfma_f32_16x16x16f16(vf[st], pf1, accB1, 0, 0, 0);
            } else {
                accA0 = __builtin_amdgcn_mfma_f32_16x16x16f16(vf[st], pf0, accA0, 0, 0, 0);
                accA1 = __builtin_amdgcn_mfma_f32_16x16x16f16(vf[st], pf1, accA1, 0, 0, 0);
            }
        }
        float rsum0 = rs0[0] + rs0[1];
        float rsum1 = rs1[0] + rs1[1];
        rsum0 += __shfl_xor(rsum0, 16);
        rsum0 += __shfl_xor(rsum0, 32);
        rsum1 += __shfl_xor(rsum1, 16);
        rsum1 += __shfl_xor(rsum1, 32);
        const float rinv0 = 1.0f / rsum0;
        const float rinv1 = 1.0f / rsum1;
        f16x4 o0, o1;
#pragma unroll
        for (int r = 0; r < 4; ++r) {
            o0[r] = (_Float16)((accA0[r] + accB0[r]) * rinv0);
            o1[r] = (_Float16)((accA1[r] + accB1[r]) * rinv1);
        }
        *(f16x4*)&X[xsw64(((tloc + j0) << 4) + l15, eh + (g << 2))] = o0;
        *(f16x4*)&X[xsw64(((tloc + j1) << 4) + l15, eh + (g << 2))] = o1;
    }
    __syncthreads();

    // ---- O-projection -> global ----
    {
        const int eo = ev;
#pragma unroll
        for (int i = 0; i < 6; ++i) {
            int tt = (wv + (i << 3)) >> 2;
            f16x8 a0 = *(const f16x8*)&X[xsw64((tt << 4) + l15, g << 3)];
            f16x8 a1 = *(const f16x8*)&X[xsw64((tt << 4) + l15, 32 + (g << 3))];
            f32x4 c = __builtin_amdgcn_mfma_f32_16x16x32_f16(a0, wo0, z, 0, 0, 0);
            c = __builtin_amdgcn_mfma_f32_16x16x32_f16(a1, wo1, c, 0, 0, 0);
#pragma unroll
            for (int r = 0; r < 4; ++r)
                outg[(((tt << 4) + (g << 2) + r) << 6) + eo] = c[r] + bov;
        }
    }
}

extern "C" void kernel_launch(void* const* d_in, const int* in_sizes, int n_in,
                              void* d_out, int out_size, void* d_ws, size_t ws_size,
                              hipStream_t stream) {
    (void)in_sizes; (void)n_in; (void)d_ws; (void)ws_size; (void)out_size;
    const int shmem = 49152;  // 48 KiB: X 24K + VT 24K
    spa_mfma4<<<2 * 192, 512, shmem, stream>>>(
        (const float*)d_in[0],
        (const float*)d_in[1], (const float*)d_in[2],
        (const float*)d_in[3], (const float*)d_in[4],
        (const float*)d_in[5], (const float*)d_in[6],
        (const float*)d_in[7], (const float*)d_in[8],
        (float*)d_out);
}